// Round 5
// baseline (511.280 us; speedup 1.0000x reference)
//
#include <hip/hip_runtime.h>
#include <hip/hip_bf16.h>

#define C 48
#define C4 192
#define HW 192
#define NPIX (HW * HW)          // 36864
#define BATCH 8
#define CNT (BATCH * NPIX)      // 294912 samples per channel for BN

// Workspace layout. Total ~85.6 MB.
#define APRE_OFF   0ull
#define G_OFF      14155776ull
#define STATS_OFF  14229504ull
#define M2_OFF     14229696ull
#define MIDT_BYTE  57213696ull
#define WB_BYTE    85525248ull

typedef __attribute__((ext_vector_type(8))) short short8;
typedef __attribute__((ext_vector_type(4))) float f32x4;

static __device__ __forceinline__ unsigned pkbf(float a, float b) {
    union { __hip_bfloat162 h; unsigned u; } t;
    t.h = __float22bfloat162_rn(make_float2(a, b));
    return t.u;                                   // low16 = bf16(a), high16 = bf16(b)
}
static __device__ __forceinline__ float lo2f(unsigned p) { return __uint_as_float(p << 16); }
static __device__ __forceinline__ float hi2f(unsigned p) { return __uint_as_float(p & 0xffff0000u); }
static __device__ __forceinline__ short f2bfs(float f) { return (short)(pkbf(f, f) & 0xffffu); }

// ---------------------------------------------------------------- k_gram_mfma
// G[s,b,c,d] = sum_n X0[b,c,n] * Xs[b,d,n] via bf16 hi/lo split MFMA (3 products).
// Round-4 post-mortem: occupancy rose (19->26%) but dur didn't (99->96us) ->
// per-wave chain is the stall: distance-1 prefetch gives loads only ~600-900
// cycles of cover vs ~1200-1500 loaded HBM latency, so every pack phase
// stalls. Round-5: prefetch distance 2 (preA/preB alternating even/odd subs,
// static indexing). Budget doubles to one full sub (+both barriers); 24 loads
// in flight per wave. LDS unchanged (52224 B, 3 blocks/CU); launch_bounds
// (256,3) keeps VGPR <= 170 so 3 waves/SIMD holds.
__global__ __launch_bounds__(256, 3) void k_gram_mfma(
    const float* __restrict__ x0, const float* __restrict__ x1,
    const float* __restrict__ x2, const float* __restrict__ x3,
    float* __restrict__ G)
{
    __shared__ short hibuf[C4 * 68];
    __shared__ short lobuf[C4 * 68];
    int b = blockIdx.y;
    int n0 = blockIdx.x * 256;
    int tid = threadIdx.x;
    int wid = tid >> 6, lane = tid & 63, col = lane & 15, quad = lane >> 4;

    const float* x0b = x0 + (size_t)b * C * NPIX;
    const float* x1b = x1 + (size_t)b * C * NPIX;
    const float* x2b = x2 + (size_t)b * C * NPIX;
    const float* x3b = x3 + (size_t)b * C * NPIX;

    f32x4 acc[3][3];
#pragma unroll
    for (int mt = 0; mt < 3; ++mt)
#pragma unroll
        for (int nt = 0; nt < 3; ++nt)
            acc[mt][nt] = (f32x4){0.f, 0.f, 0.f, 0.f};

    int scr = tid >> 4;            // 0..15: ch sub-row
    int n4 = (tid & 15) * 4;       // n offset within 64

    // Per-it source row: ch = scr + it*16 spans one source block since 16|48.
    //   s = it/3 (compile-time), c = scr + (it%3)*16.
#define GRAM_LOAD(dst, nb)                                                      \
    _Pragma("unroll")                                                           \
    for (int it = 0; it < 12; ++it) {                                           \
        const float* xb = (it / 3 == 0) ? x0b : (it / 3 == 1) ? x1b             \
                        : (it / 3 == 2) ? x2b : x3b;                            \
        dst[it] = *(const float4*)(xb + (size_t)(scr + (it % 3) * 16) * NPIX    \
                                      + (nb) + n4);                             \
    }

#define GRAM_PACK(src)                                                          \
    _Pragma("unroll")                                                           \
    for (int it = 0; it < 12; ++it) {                                           \
        int ch = scr + it * 16;                                                 \
        float4 v = src[it];                                                     \
        unsigned h01 = pkbf(v.x, v.y), h23 = pkbf(v.z, v.w);                    \
        float r0 = v.x - lo2f(h01), r1 = v.y - hi2f(h01);                       \
        float r2 = v.z - lo2f(h23), r3 = v.w - hi2f(h23);                       \
        unsigned l01 = pkbf(r0, r1), l23 = pkbf(r2, r3);                        \
        *(uint2*)&hibuf[ch * 68 + n4] = make_uint2(h01, h23);                   \
        *(uint2*)&lobuf[ch * 68 + n4] = make_uint2(l01, l23);                   \
    }

#define GRAM_MMA()                                                              \
    _Pragma("unroll")                                                           \
    for (int kb = 0; kb < 2; ++kb) {                                            \
        int ko = kb * 32 + quad * 8;                                            \
        short8 ah[3], al[3], bh[3], bl[3];                                      \
        _Pragma("unroll")                                                       \
        for (int mt = 0; mt < 3; ++mt) {                                        \
            ah[mt] = *(const short8*)&hibuf[(mt * 16 + col) * 68 + ko];         \
            al[mt] = *(const short8*)&lobuf[(mt * 16 + col) * 68 + ko];         \
        }                                                                       \
        _Pragma("unroll")                                                       \
        for (int nt = 0; nt < 3; ++nt) {                                        \
            int row = (wid * 3 + nt) * 16 + col;                                \
            bh[nt] = *(const short8*)&hibuf[row * 68 + ko];                     \
            bl[nt] = *(const short8*)&lobuf[row * 68 + ko];                     \
        }                                                                       \
        _Pragma("unroll")                                                       \
        for (int mt = 0; mt < 3; ++mt)                                          \
            _Pragma("unroll")                                                   \
            for (int nt = 0; nt < 3; ++nt) {                                    \
                acc[mt][nt] = __builtin_amdgcn_mfma_f32_16x16x32_bf16(          \
                    ah[mt], bh[nt], acc[mt][nt], 0, 0, 0);                      \
                acc[mt][nt] = __builtin_amdgcn_mfma_f32_16x16x32_bf16(          \
                    ah[mt], bl[nt], acc[mt][nt], 0, 0, 0);                      \
                acc[mt][nt] = __builtin_amdgcn_mfma_f32_16x16x32_bf16(          \
                    al[mt], bh[nt], acc[mt][nt], 0, 0, 0);                      \
            }                                                                   \
    }

    float4 preA[12], preB[12];
    GRAM_LOAD(preA, n0)            // sub 0
    GRAM_LOAD(preB, n0 + 64)       // sub 1

#pragma unroll
    for (int sp = 0; sp < 2; ++sp) {
        // even sub 2*sp: consumes preA (loaded 2 subs ago)
        GRAM_PACK(preA)
        __syncthreads();
        if (sp < 1) { GRAM_LOAD(preA, n0 + (2 * sp + 2) * 64) }
        GRAM_MMA()
        __syncthreads();
        // odd sub 2*sp+1: consumes preB
        GRAM_PACK(preB)
        __syncthreads();
        if (sp < 1) { GRAM_LOAD(preB, n0 + (2 * sp + 3) * 64) }
        GRAM_MMA()
        __syncthreads();
    }
#undef GRAM_LOAD
#undef GRAM_PACK
#undef GRAM_MMA

#pragma unroll
    for (int mt = 0; mt < 3; ++mt)
#pragma unroll
        for (int nt = 0; nt < 3; ++nt) {
            int g = (wid * 3 + nt) * 16 + col;        // 0..191 = s*48 + d
            int s = g / C, d = g - s * C;
#pragma unroll
            for (int j = 0; j < 4; ++j) {
                int c = mt * 16 + quad * 4 + j;
                atomicAdd(&G[(((size_t)s * BATCH + b) * C + c) * C + d],
                          acc[mt][nt][j]);
            }
        }
}

// ---------------------------------------------------------------- k_small
__global__ __launch_bounds__(256) void k_small(
    const float* __restrict__ G,
    const float* __restrict__ Wa, const float* __restrict__ Wb,
    const float* __restrict__ Wc, const float* __restrict__ Wd,
    const float* __restrict__ fuse_w, float* __restrict__ M2g)
{
    int s = blockIdx.x, b = blockIdx.y;
    const float* Ws = (s == 0) ? Wa : (s == 1) ? Wb : (s == 2) ? Wc : Wd;

    __shared__ float g[C * C], wsm[C * C], wam[C * C], fw[C * C];
    __shared__ float t[C * C], e[C * C], m[C * C];
    int tid = threadIdx.x;

    const float* Gb = G + ((size_t)s * BATCH + b) * C * C;
    for (int k = tid; k < C * C; k += 256) {
        g[k] = Gb[k];
        wsm[k] = Ws[k];
        wam[k] = Wa[k];
        int o = k / C, c = k % C;
        fw[k] = fuse_w[(size_t)o * C4 + s * C + c];
    }
    __syncthreads();

    for (int k = tid; k < C * C; k += 256) {
        int c = k / C, d = k % C;
        float a = 0.f;
        for (int q = 0; q < C; ++q) a += g[c * C + q] * wsm[d * C + q];
        t[k] = a;
    }
    __syncthreads();
    for (int k = tid; k < C * C; k += 256) {
        int c = k / C, d = k % C;
        float a = 0.f;
        for (int q = 0; q < C; ++q) a += wam[c * C + q] * t[q * C + d];
        e[k] = a;
    }
    __syncthreads();
    if (tid < C) {
        int c = tid;
        float mn = e[c * C];
        for (int d = 1; d < C; ++d) mn = fminf(mn, e[c * C + d]);
        float sum = 0.f;
        for (int d = 0; d < C; ++d) {
            float v = __expf(mn - e[c * C + d]);
            e[c * C + d] = v;
            sum += v;
        }
        float inv = 1.0f / sum;
        for (int d = 0; d < C; ++d) e[c * C + d] *= inv;
    }
    __syncthreads();
    for (int k = tid; k < C * C; k += 256) {
        int d = k / C, o = k % C;
        float a = 0.f;
        for (int q = 0; q < C; ++q) a += fw[o * C + q] * e[q * C + d];
        m[k] = a;
    }
    __syncthreads();
    float* out = M2g + ((size_t)b * 4 + s) * C * C;
    for (int k = tid; k < C * C; k += 256) {
        int c = k / C, o = k % C;
        float a = 0.f;
        for (int q = 0; q < C; ++q) a += wsm[q * C + c] * m[q * C + o];
        out[k] = a;
    }
}

// ---------------------------------------------------------------- k_apply_mfma
// apre[b,o,n] = sum_{k=0..191} M2[b][k][o] * X[k][n] + fuse_b[o]  via MFMA.
//  * X tiles (64 n x 192 ch) staged in LDS via coalesced float4 loads
//    (2 adjacent channels x 4 pixels per thread -> channel-pair-packed dwords,
//    transposed [n][ch] rows). No more 8x scalar stride-NPIX gathers.
//  * Row stride 512 B + within-row XOR swizzle f=((row>>1)^(row>>2))&7 applied
//    as x ^= f<<4: both ds_write_b32 (2-way) and ds_read_b128 (8 acc/bank) hit
//    the wave64 bank-conflict minimum; bijective, in-bounds by construction.
//  * Compact K=192 (6 kq, channel runs may cross source boundaries inside LDS)
//    -> 18 MFMA per 16-n slice instead of 24 (no zero padding).
//  * Chunk 256 n -> grid 144x8 = 1152 blocks: 4.5 blocks/CU.
//  * BN stats: block-level LDS reduction, then 96 global atomics per block.
static __device__ __forceinline__ unsigned ladr(unsigned row, unsigned x) {
    unsigned f = ((row >> 1) ^ (row >> 2)) & 7;
    return (row << 9) | (x ^ (f << 4));
}

__global__ __launch_bounds__(256) void k_apply_mfma(
    const float* __restrict__ x0, const float* __restrict__ x1,
    const float* __restrict__ x2, const float* __restrict__ x3,
    const float* __restrict__ M2g, const float* __restrict__ fuse_b,
    float* __restrict__ apre, float* __restrict__ stats)
{
    __shared__ __align__(16) char xbuf[64 * 512];  // A-phase: [48 o][k192]; tiles: [64 n][192 ch]
    __shared__ float sst[96];
    char* lb = xbuf;

    int b = blockIdx.y;
    int n0 = blockIdx.x * 256;
    int tid = threadIdx.x;
    int wid = tid >> 6, lane = tid & 63, col = lane & 15, quad = lane >> 4;

    const float* x0b = x0 + (size_t)b * C * NPIX;
    const float* x1b = x1 + (size_t)b * C * NPIX;
    const float* x2b = x2 + (size_t)b * C * NPIX;
    const float* x3b = x3 + (size_t)b * C * NPIX;

    if (tid < 96) sst[tid] = 0.f;

    // ---- A = M2 (k = s*48+c compact, rows = o) into LDS as bf16
    const float* Mb = M2g + (size_t)b * 4 * C * C;
    for (int e = tid; e < 48 * 192; e += 256) {
        int k = e / 48, o = e - k * 48;            // consecutive lanes -> consecutive o (coalesced)
        *(short*)(lb + ladr(o, k * 2)) = f2bfs(Mb[(size_t)k * 48 + o]);
    }
    __syncthreads();

    short8 afr[3][6];
#pragma unroll
    for (int mt = 0; mt < 3; ++mt)
#pragma unroll
        for (int kq = 0; kq < 6; ++kq)
            afr[mt][kq] = *(const short8*)(lb + ladr(mt * 16 + col, kq * 64 + quad * 16));

    float fbv[3][4];
#pragma unroll
    for (int mt = 0; mt < 3; ++mt)
#pragma unroll
        for (int j = 0; j < 4; ++j)
            fbv[mt][j] = fuse_b[mt * 16 + quad * 4 + j];

    float s1[3][4] = {}, s2[3][4] = {};
    int nl = (wid << 4) + col;

    for (int sub = 0; sub < 4; ++sub) {
        int nb = n0 + sub * 64;
        __syncthreads();                            // prior tile's reads (or afr hoist) done
#pragma unroll
        for (int it = 0; it < 6; ++it) {
            int ef = tid + it * 256;                // 0..1535
            int p  = ef >> 4;                       // channel pair 0..95
            int nq = (ef & 15) << 2;                // 0..60
            int s  = p / 24;
            int c2 = (p - s * 24) * 2;
            const float* xp = ((s == 0) ? x0b : (s == 1) ? x1b : (s == 2) ? x2b : x3b)
                              + (size_t)c2 * NPIX + nb + nq;
            float4 va = *(const float4*)xp;         // channel c2,   n..n+3
            float4 vb = *(const float4*)(xp + NPIX);// channel c2+1, n..n+3
            unsigned p4 = (unsigned)p * 4;
            *(unsigned*)(lb + ladr(nq + 0, p4)) = pkbf(va.x, vb.x);
            *(unsigned*)(lb + ladr(nq + 1, p4)) = pkbf(va.y, vb.y);
            *(unsigned*)(lb + ladr(nq + 2, p4)) = pkbf(va.z, vb.z);
            *(unsigned*)(lb + ladr(nq + 3, p4)) = pkbf(va.w, vb.w);
        }
        __syncthreads();

        f32x4 acc[3];
        acc[0] = (f32x4){0.f, 0.f, 0.f, 0.f};
        acc[1] = (f32x4){0.f, 0.f, 0.f, 0.f};
        acc[2] = (f32x4){0.f, 0.f, 0.f, 0.f};
#pragma unroll
        for (int kq = 0; kq < 6; ++kq) {
            short8 bfr = *(const short8*)(lb + ladr(nl, kq * 64 + quad * 16));
            acc[0] = __builtin_amdgcn_mfma_f32_16x16x32_bf16(afr[0][kq], bfr, acc[0], 0, 0, 0);
            acc[1] = __builtin_amdgcn_mfma_f32_16x16x32_bf16(afr[1][kq], bfr, acc[1], 0, 0, 0);
            acc[2] = __builtin_amdgcn_mfma_f32_16x16x32_bf16(afr[2][kq], bfr, acc[2], 0, 0, 0);
        }

        int n = nb + nl;
#pragma unroll
        for (int mt = 0; mt < 3; ++mt)
#pragma unroll
            for (int j = 0; j < 4; ++j) {
                int o = mt * 16 + quad * 4 + j;
                float val = acc[mt][j] + fbv[mt][j];
                apre[((size_t)b * C + o) * NPIX + n] = val;
                s1[mt][j] += val;
                s2[mt][j] += val * val;
            }
    }

#pragma unroll
    for (int mt = 0; mt < 3; ++mt)
#pragma unroll
        for (int j = 0; j < 4; ++j) {
            float a = s1[mt][j], q = s2[mt][j];
#pragma unroll
            for (int off = 8; off; off >>= 1) {
                a += __shfl_down(a, off, 16);
                q += __shfl_down(q, off, 16);
            }
            if (col == 0) {
                int o = mt * 16 + quad * 4 + j;
                atomicAdd(&sst[o], a);
                atomicAdd(&sst[48 + o], q);
            }
        }
    __syncthreads();
    if (tid < 96) atomicAdd(&stats[tid], sst[tid]);   // stats[o], stats[C+o] are contiguous
}

// ---------------------------------------------------------------- k_bn1t
// mid_t[b,px,c] = bf16(gamma_cam*relu(BN(apre)) + input); LDS tile-transpose
// makes the global bf16 store a contiguous short4 stream.
__global__ __launch_bounds__(256) void k_bn1t(
    const float* __restrict__ apre, const float* __restrict__ inp,
    const float* __restrict__ stats, const float* __restrict__ gamma,
    const float* __restrict__ beta, const float* __restrict__ gcam,
    short* __restrict__ mid_t)
{
    __shared__ short t[64 * C];     // [px_local][c]
    int b = blockIdx.y;
    int n0 = blockIdx.x * 64;
    int tid = threadIdx.x;
    const float invc = 1.0f / (float)CNT;
    float g = gcam[0];

#pragma unroll
    for (int it = 0; it < 3; ++it) {
        int e = tid + it * 256;                 // 0..767 = 48 ch x 16 px-quads
        int c = e >> 4, pq = (e & 15) * 4;
        float mu = stats[c] * invc;
        float var = stats[C + c] * invc - mu * mu;
        float sc = gamma[c] * rsqrtf(var + 1e-5f);
        float be = beta[c] - mu * sc;
        size_t base = ((size_t)b * C + c) * NPIX + n0 + pq;
        float4 v = *(const float4*)(apre + base);
        float4 x = *(const float4*)(inp + base);
        t[(pq + 0) * C + c] = f2bfs(fmaxf(v.x * sc + be, 0.f) * g + x.x);
        t[(pq + 1) * C + c] = f2bfs(fmaxf(v.y * sc + be, 0.f) * g + x.y);
        t[(pq + 2) * C + c] = f2bfs(fmaxf(v.z * sc + be, 0.f) * g + x.z);
        t[(pq + 3) * C + c] = f2bfs(fmaxf(v.w * sc + be, 0.f) * g + x.w);
    }
    __syncthreads();
    short* mb = mid_t + ((size_t)b * NPIX + n0) * C;
#pragma unroll
    for (int it = 0; it < 3; ++it) {
        int e = tid + it * 256;                 // contiguous: row = 12 short4s
        *(short4*)(mb + e * 4) = *(const short4*)&t[e * 4];
    }
}

// ---------------------------------------------------------------- k_prep
__global__ __launch_bounds__(256) void k_prep(
    const float* __restrict__ outw, short* __restrict__ Wb)
{
    int idx = blockIdx.x * 256 + threadIdx.x;
    if (idx >= 9 * 48 * 64) return;
    int i = idx & 63;
    int o = (idx >> 6) % 48;
    int tap = idx / (64 * 48);
    float v = (i < C) ? outw[((size_t)o * C + i) * 9 + tap] : 0.f;
    Wb[idx] = f2bfs(v);
}

// ---------------------------------------------------------------- k_conv_mfma
__global__ __launch_bounds__(256) void k_conv_mfma(
    const short* __restrict__ mid_t, const short* __restrict__ Wb,
    const float* __restrict__ bias, float* __restrict__ out,
    float* __restrict__ stats)
{
    __shared__ short xl[324 * 72];
    __shared__ float sst[96];
    int b = blockIdx.y;
    int ty = blockIdx.x / 12, tx = blockIdx.x % 12;
    int h0 = ty * 16, w0 = tx * 16;
    int tid = threadIdx.x;

    if (tid < 96) sst[tid] = 0.f;

    for (int ch = tid; ch < 2916; ch += 256) {
        int lpx = ch / 9, part = ch % 9;
        int hh = h0 - 1 + lpx / 18, ww = w0 - 1 + lpx % 18;
        short8 v = {0, 0, 0, 0, 0, 0, 0, 0};
        if (part < 6 && hh >= 0 && hh < HW && ww >= 0 && ww < HW)
            v = *(const short8*)(mid_t + ((size_t)b * NPIX + hh * HW + ww) * C + part * 8);
        *(short8*)(xl + lpx * 72 + part * 8) = v;
    }
    __syncthreads();

    int wid = tid >> 6, lane = tid & 63;
    int col = lane & 15, quad = lane >> 4;

    f32x4 acc[3][4];
#pragma unroll
    for (int mt = 0; mt < 3; ++mt)
#pragma unroll
        for (int rr = 0; rr < 4; ++rr)
            acc[mt][rr] = (f32x4){0.f, 0.f, 0.f, 0.f};

#pragma unroll
    for (int tap = 0; tap < 9; ++tap) {
        int dh = tap / 3, dw = tap % 3;
#pragma unroll
        for (int kb = 0; kb < 2; ++kb) {
            short8 afr[3];
#pragma unroll
            for (int mt = 0; mt < 3; ++mt)
                afr[mt] = *(const short8*)(Wb + ((size_t)(tap * 48 + mt * 16 + col)) * 64
                                               + kb * 32 + quad * 8);
#pragma unroll
            for (int rr = 0; rr < 4; ++rr) {
                int r = wid * 4 + rr;
                int lpx = (r + dh) * 18 + col + dw;
                short8 bfr = *(const short8*)(xl + lpx * 72 + kb * 32 + quad * 8);
#pragma unroll
                for (int mt = 0; mt < 3; ++mt)
                    acc[mt][rr] = __builtin_amdgcn_mfma_f32_16x16x32_bf16(
                        afr[mt], bfr, acc[mt][rr], 0, 0, 0);
            }
        }
    }

    float s1[3][4] = {}, s2[3][4] = {};
#pragma unroll
    for (int mt = 0; mt < 3; ++mt)
#pragma unroll
        for (int rr = 0; rr < 4; ++rr) {
            int r = wid * 4 + rr;
            f32x4 v = acc[mt][rr];
#pragma unroll
            for (int j = 0; j < 4; ++j) {
                int o = mt * 16 + quad * 4 + j;
                float val = v[j] + bias[o];
                out[((size_t)b * C + o) * NPIX + (h0 + r) * HW + w0 + col] = val;
                s1[mt][j] += val;
                s2[mt][j] += val * val;
            }
        }
#pragma unroll
    for (int mt = 0; mt < 3; ++mt)
#pragma unroll
        for (int j = 0; j < 4; ++j) {
            float a = s1[mt][j], q = s2[mt][j];
#pragma unroll
            for (int off = 8; off; off >>= 1) {
                a += __shfl_down(a, off, 16);
                q += __shfl_down(q, off, 16);
            }
            if (col == 0) {
                int o = mt * 16 + quad * 4 + j;
                atomicAdd(&sst[o], a);
                atomicAdd(&sst[48 + o], q);
            }
        }
    __syncthreads();
    if (tid < 48)       atomicAdd(&stats[2 * C + tid], sst[tid]);
    else if (tid < 96)  atomicAdd(&stats[3 * C + tid - 48], sst[tid]);
}

// ---------------------------------------------------------------- k_bn2
__global__ __launch_bounds__(256) void k_bn2(
    float* __restrict__ out, const float* __restrict__ stats,
    const float* __restrict__ gamma, const float* __restrict__ beta)
{
    size_t i = ((size_t)blockIdx.x * 256 + threadIdx.x) * 4;
    int c = (int)((i / NPIX) % C);
    const float invc = 1.0f / (float)CNT;
    float mu = stats[2 * C + c] * invc;
    float var = stats[3 * C + c] * invc - mu * mu;
    float sc = gamma[c] * rsqrtf(var + 1e-5f);
    float be = beta[c] - mu * sc;

    float4 v = *(float4*)(out + i);
    v.x = fmaxf(v.x * sc + be, 0.f);
    v.y = fmaxf(v.y * sc + be, 0.f);
    v.z = fmaxf(v.z * sc + be, 0.f);
    v.w = fmaxf(v.w * sc + be, 0.f);
    *(float4*)(out + i) = v;
}

// ---------------------------------------------------------------- launch
extern "C" void kernel_launch(void* const* d_in, const int* in_sizes, int n_in,
                              void* d_out, int out_size, void* d_ws, size_t ws_size,
                              hipStream_t stream)
{
    const float* inp   = (const float*)d_in[0];
    const float* fb    = (const float*)d_in[1];
    const float* fc    = (const float*)d_in[2];
    const float* fd    = (const float*)d_in[3];
    const float* Wa    = (const float*)d_in[4];
    const float* Wbm   = (const float*)d_in[5];
    const float* Wcm   = (const float*)d_in[6];
    const float* Wdm   = (const float*)d_in[7];
    const float* fusew = (const float*)d_in[8];
    const float* fuseb = (const float*)d_in[9];
    const float* fgam  = (const float*)d_in[10];
    const float* fbet  = (const float*)d_in[11];
    const float* gcam  = (const float*)d_in[12];
    const float* outw  = (const float*)d_in[13];
    const float* outb  = (const float*)d_in[14];
    const float* ogam  = (const float*)d_in[15];
    const float* obet  = (const float*)d_in[16];

    float* ws    = (float*)d_ws;
    float* apre  = ws + APRE_OFF;
    float* G     = ws + G_OFF;
    float* stats = ws + STATS_OFF;
    float* M2g   = ws + M2_OFF;
    short* mid_t = (short*)((char*)d_ws + MIDT_BYTE);
    short* Wb    = (short*)((char*)d_ws + WB_BYTE);
    float* out   = (float*)d_out;

    hipMemsetAsync(G, 0, (73728ull + 192ull) * sizeof(float), stream);

    k_prep<<<108, 256, 0, stream>>>(outw, Wb);
    k_gram_mfma<<<dim3(144, BATCH), 256, 0, stream>>>(inp, fb, fc, fd, G);
    k_small<<<dim3(4, BATCH), 256, 0, stream>>>(G, Wa, Wbm, Wcm, Wdm, fusew, M2g);
    k_apply_mfma<<<dim3(144, BATCH), 256, 0, stream>>>(inp, fb, fc, fd, M2g, fuseb, apre, stats);
    k_bn1t<<<dim3(576, BATCH), 256, 0, stream>>>(apre, inp, stats, fgam, fbet, gcam, mid_t);
    k_conv_mfma<<<dim3(144, BATCH), 256, 0, stream>>>(mid_t, Wb, outb, out, stats);
    k_bn2<<<13824, 256, 0, stream>>>(out, stats, ogam, obet);
}

// Round 6
// 477.316 us; speedup vs baseline: 1.0712x; 1.0712x over previous
//
#include <hip/hip_runtime.h>
#include <hip/hip_bf16.h>

#define C 48
#define C4 192
#define HW 192
#define NPIX (HW * HW)          // 36864
#define BATCH 8
#define CNT (BATCH * NPIX)      // 294912 samples per channel for BN

// Workspace layout. Total ~85.6 MB.
#define APRE_OFF   0ull
#define G_OFF      14155776ull
#define STATS_OFF  14229504ull
#define M2_OFF     14229696ull
#define MIDT_BYTE  57213696ull
#define WB_BYTE    85525248ull

typedef __attribute__((ext_vector_type(8))) short short8;
typedef __attribute__((ext_vector_type(4))) float f32x4;

static __device__ __forceinline__ unsigned pkbf(float a, float b) {
    union { __hip_bfloat162 h; unsigned u; } t;
    t.h = __float22bfloat162_rn(make_float2(a, b));
    return t.u;                                   // low16 = bf16(a), high16 = bf16(b)
}
static __device__ __forceinline__ float lo2f(unsigned p) { return __uint_as_float(p << 16); }
static __device__ __forceinline__ float hi2f(unsigned p) { return __uint_as_float(p & 0xffff0000u); }
static __device__ __forceinline__ short f2bfs(float f) { return (short)(pkbf(f, f) & 0xffffu); }

// 8 fp32 -> bf16 hi frag + residual lo frag (identical roundings to prior kernel)
static __device__ __forceinline__ void pk8(f32x4 g0, f32x4 g1, short8& hi, short8& lo) {
    union { short8 s; unsigned u[4]; } H, L;
    H.u[0] = pkbf(g0[0], g0[1]); H.u[1] = pkbf(g0[2], g0[3]);
    H.u[2] = pkbf(g1[0], g1[1]); H.u[3] = pkbf(g1[2], g1[3]);
    L.u[0] = pkbf(g0[0] - lo2f(H.u[0]), g0[1] - hi2f(H.u[0]));
    L.u[1] = pkbf(g0[2] - lo2f(H.u[1]), g0[3] - hi2f(H.u[1]));
    L.u[2] = pkbf(g1[0] - lo2f(H.u[2]), g1[1] - hi2f(H.u[2]));
    L.u[3] = pkbf(g1[2] - lo2f(H.u[3]), g1[3] - hi2f(H.u[3]));
    hi = H.s; lo = L.s;
}

// ---------------------------------------------------------------- k_gram_mfma
// G[s,b,c,d] = sum_n X0[b,c,n] * Xs[b,d,n] via bf16 hi/lo split MFMA.
// Round-6 rewrite (m97/T3-lite DMA pipeline):
//  * fp32 32-n tiles DMA'd to LDS via global_load_lds width=16 (6 insts/wave,
//    wave w stages source w's 48 rows). Double-buffered; tile t+1 issued
//    before computing tile t; drained by counted s_waitcnt vmcnt(6) + raw
//    s_barrier (never vmcnt(0) mid-loop). Zero VGPR prefetch state -> no
//    spill (round-5 lesson: WRITE_SIZE +66MB was scratch).
//  * Both-sides swizzle (rule #21): LDS linear (DMA requires), per-lane
//    GLOBAL granule pre-swizzled slot=(lane&7)^(lane>>3); reads XOR row&7
//    (=col&7 for all fragment rows). ds_read_b128 lands 2 lanes/bank = free
//    (unswizzled 128-B rows would be 16-way conflicted).
//  * bf16 hi/lo pack moved into the register path (pk8) -> the pack-write
//    phase and one barrier per sub are gone. Same roundings, same
//    per-element accumulation order as the passing kernel.
//  * LDS 2x24 KB = 48 KB -> 3 blocks/CU; launch_bounds(256,2) caps VGPR at
//    128 so a forced spill cannot recur.
__global__ __launch_bounds__(256, 2) void k_gram_mfma(
    const float* __restrict__ x0, const float* __restrict__ x1,
    const float* __restrict__ x2, const float* __restrict__ x3,
    float* __restrict__ G)
{
    __shared__ float tile[2][192 * 32];   // [buf][row*32 + n], 128-B rows, linear
    int b = blockIdx.y;
    int n0 = blockIdx.x * 256;
    int tid = threadIdx.x;
    int wid = tid >> 6, lane = tid & 63, col = lane & 15, quad = lane >> 4;

    const float* x0b = x0 + (size_t)b * C * NPIX;
    const float* x1b = x1 + (size_t)b * C * NPIX;
    const float* x2b = x2 + (size_t)b * C * NPIX;
    const float* x3b = x3 + (size_t)b * C * NPIX;
    const float* xw = (wid == 0) ? x0b : (wid == 1) ? x1b : (wid == 2) ? x2b : x3b;

    // DMA source per lane: row c = 8j + (lane>>3) of source wid, 16-B granule
    // (lane&7) ^ (lane>>3); DMA writes LDS linearly at dst + lane*16, so
    // LDS[row][g] holds global granule g ^ (row%8).
    int r8 = lane >> 3;
    int sl = (lane & 7) ^ r8;
    const float* srcbase = xw + (size_t)r8 * NPIX + sl * 4;

    f32x4 acc[3][3];
#pragma unroll
    for (int mt = 0; mt < 3; ++mt)
#pragma unroll
        for (int nt = 0; nt < 3; ++nt)
            acc[mt][nt] = (f32x4){0.f, 0.f, 0.f, 0.f};

    int r7 = col & 7;
    int q2 = quad * 2;

#define STAGE(buf, nb)                                                          \
    {                                                                           \
        char* dstb = (char*)&tile[buf][0] + wid * 6144;                         \
        const float* sb = srcbase + (nb);                                       \
        _Pragma("unroll")                                                       \
        for (int j = 0; j < 6; ++j)                                             \
            __builtin_amdgcn_global_load_lds(                                   \
                (const __attribute__((address_space(1))) void*)                 \
                    (sb + (size_t)8 * j * NPIX),                                \
                (__attribute__((address_space(3))) void*)(dstb + j * 1024),     \
                16, 0, 0);                                                      \
    }

#define COMPUTE(buf)                                                            \
    {                                                                           \
        const char* tb = (const char*)&tile[buf][0];                            \
        short8 ah[3], al[3];                                                    \
        _Pragma("unroll")                                                       \
        for (int mt = 0; mt < 3; ++mt) {                                        \
            int row = mt * 16 + col;                                            \
            f32x4 g0 = *(const f32x4*)(tb + row * 128 + ((q2 ^ r7) << 4));      \
            f32x4 g1 = *(const f32x4*)(tb + row * 128 + (((q2 + 1) ^ r7) << 4));\
            pk8(g0, g1, ah[mt], al[mt]);                                        \
        }                                                                       \
        _Pragma("unroll")                                                       \
        for (int nt = 0; nt < 3; ++nt) {                                        \
            int row = (wid * 3 + nt) * 16 + col;                                \
            f32x4 g0 = *(const f32x4*)(tb + row * 128 + ((q2 ^ r7) << 4));      \
            f32x4 g1 = *(const f32x4*)(tb + row * 128 + (((q2 + 1) ^ r7) << 4));\
            short8 bh, bl;                                                      \
            pk8(g0, g1, bh, bl);                                                \
            _Pragma("unroll")                                                   \
            for (int mt = 0; mt < 3; ++mt) {                                    \
                acc[mt][nt] = __builtin_amdgcn_mfma_f32_16x16x32_bf16(          \
                    ah[mt], bh, acc[mt][nt], 0, 0, 0);                          \
                acc[mt][nt] = __builtin_amdgcn_mfma_f32_16x16x32_bf16(          \
                    ah[mt], bl, acc[mt][nt], 0, 0, 0);                          \
                acc[mt][nt] = __builtin_amdgcn_mfma_f32_16x16x32_bf16(          \
                    al[mt], bh, acc[mt][nt], 0, 0, 0);                          \
            }                                                                   \
        }                                                                       \
    }

    STAGE(0, n0)                              // prologue: tile 0 in flight
    for (int t = 0; t < 8; ++t) {
        if (t < 7) {
            STAGE((t + 1) & 1, n0 + (t + 1) * 32)      // issue next tile
            asm volatile("s_waitcnt vmcnt(6)" ::: "memory");  // tile t done
        } else {
            asm volatile("s_waitcnt vmcnt(0)" ::: "memory");
        }
        __builtin_amdgcn_sched_barrier(0);
        __builtin_amdgcn_s_barrier();         // all waves' tile-t DMA visible
        __builtin_amdgcn_sched_barrier(0);
        COMPUTE(t & 1)                        // ds_read fp32 + pack + 27 MFMA
        __builtin_amdgcn_s_barrier();         // reads done before overwrite
        __builtin_amdgcn_sched_barrier(0);
    }
#undef STAGE
#undef COMPUTE

#pragma unroll
    for (int mt = 0; mt < 3; ++mt)
#pragma unroll
        for (int nt = 0; nt < 3; ++nt) {
            int g = (wid * 3 + nt) * 16 + col;        // 0..191 = s*48 + d
            int s = g / C, d = g - s * C;
#pragma unroll
            for (int j = 0; j < 4; ++j) {
                int c = mt * 16 + quad * 4 + j;
                atomicAdd(&G[(((size_t)s * BATCH + b) * C + c) * C + d],
                          acc[mt][nt][j]);
            }
        }
}

// ---------------------------------------------------------------- k_small
__global__ __launch_bounds__(256) void k_small(
    const float* __restrict__ G,
    const float* __restrict__ Wa, const float* __restrict__ Wb,
    const float* __restrict__ Wc, const float* __restrict__ Wd,
    const float* __restrict__ fuse_w, float* __restrict__ M2g)
{
    int s = blockIdx.x, b = blockIdx.y;
    const float* Ws = (s == 0) ? Wa : (s == 1) ? Wb : (s == 2) ? Wc : Wd;

    __shared__ float g[C * C], wsm[C * C], wam[C * C], fw[C * C];
    __shared__ float t[C * C], e[C * C], m[C * C];
    int tid = threadIdx.x;

    const float* Gb = G + ((size_t)s * BATCH + b) * C * C;
    for (int k = tid; k < C * C; k += 256) {
        g[k] = Gb[k];
        wsm[k] = Ws[k];
        wam[k] = Wa[k];
        int o = k / C, c = k % C;
        fw[k] = fuse_w[(size_t)o * C4 + s * C + c];
    }
    __syncthreads();

    for (int k = tid; k < C * C; k += 256) {
        int c = k / C, d = k % C;
        float a = 0.f;
        for (int q = 0; q < C; ++q) a += g[c * C + q] * wsm[d * C + q];
        t[k] = a;
    }
    __syncthreads();
    for (int k = tid; k < C * C; k += 256) {
        int c = k / C, d = k % C;
        float a = 0.f;
        for (int q = 0; q < C; ++q) a += wam[c * C + q] * t[q * C + d];
        e[k] = a;
    }
    __syncthreads();
    if (tid < C) {
        int c = tid;
        float mn = e[c * C];
        for (int d = 1; d < C; ++d) mn = fminf(mn, e[c * C + d]);
        float sum = 0.f;
        for (int d = 0; d < C; ++d) {
            float v = __expf(mn - e[c * C + d]);
            e[c * C + d] = v;
            sum += v;
        }
        float inv = 1.0f / sum;
        for (int d = 0; d < C; ++d) e[c * C + d] *= inv;
    }
    __syncthreads();
    for (int k = tid; k < C * C; k += 256) {
        int d = k / C, o = k % C;
        float a = 0.f;
        for (int q = 0; q < C; ++q) a += fw[o * C + q] * e[q * C + d];
        m[k] = a;
    }
    __syncthreads();
    float* out = M2g + ((size_t)b * 4 + s) * C * C;
    for (int k = tid; k < C * C; k += 256) {
        int c = k / C, o = k % C;
        float a = 0.f;
        for (int q = 0; q < C; ++q) a += wsm[q * C + c] * m[q * C + o];
        out[k] = a;
    }
}

// ---------------------------------------------------------------- k_apply_mfma
// apre[b,o,n] = sum_{k=0..191} M2[b][k][o] * X[k][n] + fuse_b[o]  via MFMA.
//  * X tiles (64 n x 192 ch) staged in LDS via coalesced float4 loads
//    (2 adjacent channels x 4 pixels per thread -> channel-pair-packed dwords,
//    transposed [n][ch] rows). No more 8x scalar stride-NPIX gathers.
//  * Row stride 512 B + within-row XOR swizzle f=((row>>1)^(row>>2))&7 applied
//    as x ^= f<<4: both ds_write_b32 (2-way) and ds_read_b128 (8 acc/bank) hit
//    the wave64 bank-conflict minimum; bijective, in-bounds by construction.
//  * Compact K=192 (6 kq, channel runs may cross source boundaries inside LDS)
//    -> 18 MFMA per 16-n slice instead of 24 (no zero padding).
//  * Chunk 256 n -> grid 144x8 = 1152 blocks: 4.5 blocks/CU.
//  * BN stats: block-level LDS reduction, then 96 global atomics per block.
static __device__ __forceinline__ unsigned ladr(unsigned row, unsigned x) {
    unsigned f = ((row >> 1) ^ (row >> 2)) & 7;
    return (row << 9) | (x ^ (f << 4));
}

__global__ __launch_bounds__(256) void k_apply_mfma(
    const float* __restrict__ x0, const float* __restrict__ x1,
    const float* __restrict__ x2, const float* __restrict__ x3,
    const float* __restrict__ M2g, const float* __restrict__ fuse_b,
    float* __restrict__ apre, float* __restrict__ stats)
{
    __shared__ __align__(16) char xbuf[64 * 512];  // A-phase: [48 o][k192]; tiles: [64 n][192 ch]
    __shared__ float sst[96];
    char* lb = xbuf;

    int b = blockIdx.y;
    int n0 = blockIdx.x * 256;
    int tid = threadIdx.x;
    int wid = tid >> 6, lane = tid & 63, col = lane & 15, quad = lane >> 4;

    const float* x0b = x0 + (size_t)b * C * NPIX;
    const float* x1b = x1 + (size_t)b * C * NPIX;
    const float* x2b = x2 + (size_t)b * C * NPIX;
    const float* x3b = x3 + (size_t)b * C * NPIX;

    if (tid < 96) sst[tid] = 0.f;

    // ---- A = M2 (k = s*48+c compact, rows = o) into LDS as bf16
    const float* Mb = M2g + (size_t)b * 4 * C * C;
    for (int e = tid; e < 48 * 192; e += 256) {
        int k = e / 48, o = e - k * 48;            // consecutive lanes -> consecutive o (coalesced)
        *(short*)(lb + ladr(o, k * 2)) = f2bfs(Mb[(size_t)k * 48 + o]);
    }
    __syncthreads();

    short8 afr[3][6];
#pragma unroll
    for (int mt = 0; mt < 3; ++mt)
#pragma unroll
        for (int kq = 0; kq < 6; ++kq)
            afr[mt][kq] = *(const short8*)(lb + ladr(mt * 16 + col, kq * 64 + quad * 16));

    float fbv[3][4];
#pragma unroll
    for (int mt = 0; mt < 3; ++mt)
#pragma unroll
        for (int j = 0; j < 4; ++j)
            fbv[mt][j] = fuse_b[mt * 16 + quad * 4 + j];

    float s1[3][4] = {}, s2[3][4] = {};
    int nl = (wid << 4) + col;

    for (int sub = 0; sub < 4; ++sub) {
        int nb = n0 + sub * 64;
        __syncthreads();                            // prior tile's reads (or afr hoist) done
#pragma unroll
        for (int it = 0; it < 6; ++it) {
            int ef = tid + it * 256;                // 0..1535
            int p  = ef >> 4;                       // channel pair 0..95
            int nq = (ef & 15) << 2;                // 0..60
            int s  = p / 24;
            int c2 = (p - s * 24) * 2;
            const float* xp = ((s == 0) ? x0b : (s == 1) ? x1b : (s == 2) ? x2b : x3b)
                              + (size_t)c2 * NPIX + nb + nq;
            float4 va = *(const float4*)xp;         // channel c2,   n..n+3
            float4 vb = *(const float4*)(xp + NPIX);// channel c2+1, n..n+3
            unsigned p4 = (unsigned)p * 4;
            *(unsigned*)(lb + ladr(nq + 0, p4)) = pkbf(va.x, vb.x);
            *(unsigned*)(lb + ladr(nq + 1, p4)) = pkbf(va.y, vb.y);
            *(unsigned*)(lb + ladr(nq + 2, p4)) = pkbf(va.z, vb.z);
            *(unsigned*)(lb + ladr(nq + 3, p4)) = pkbf(va.w, vb.w);
        }
        __syncthreads();

        f32x4 acc[3];
        acc[0] = (f32x4){0.f, 0.f, 0.f, 0.f};
        acc[1] = (f32x4){0.f, 0.f, 0.f, 0.f};
        acc[2] = (f32x4){0.f, 0.f, 0.f, 0.f};
#pragma unroll
        for (int kq = 0; kq < 6; ++kq) {
            short8 bfr = *(const short8*)(lb + ladr(nl, kq * 64 + quad * 16));
            acc[0] = __builtin_amdgcn_mfma_f32_16x16x32_bf16(afr[0][kq], bfr, acc[0], 0, 0, 0);
            acc[1] = __builtin_amdgcn_mfma_f32_16x16x32_bf16(afr[1][kq], bfr, acc[1], 0, 0, 0);
            acc[2] = __builtin_amdgcn_mfma_f32_16x16x32_bf16(afr[2][kq], bfr, acc[2], 0, 0, 0);
        }

        int n = nb + nl;
#pragma unroll
        for (int mt = 0; mt < 3; ++mt)
#pragma unroll
            for (int j = 0; j < 4; ++j) {
                int o = mt * 16 + quad * 4 + j;
                float val = acc[mt][j] + fbv[mt][j];
                apre[((size_t)b * C + o) * NPIX + n] = val;
                s1[mt][j] += val;
                s2[mt][j] += val * val;
            }
    }

#pragma unroll
    for (int mt = 0; mt < 3; ++mt)
#pragma unroll
        for (int j = 0; j < 4; ++j) {
            float a = s1[mt][j], q = s2[mt][j];
#pragma unroll
            for (int off = 8; off; off >>= 1) {
                a += __shfl_down(a, off, 16);
                q += __shfl_down(q, off, 16);
            }
            if (col == 0) {
                int o = mt * 16 + quad * 4 + j;
                atomicAdd(&sst[o], a);
                atomicAdd(&sst[48 + o], q);
            }
        }
    __syncthreads();
    if (tid < 96) atomicAdd(&stats[tid], sst[tid]);   // stats[o], stats[C+o] are contiguous
}

// ---------------------------------------------------------------- k_bn1t
// mid_t[b,px,c] = bf16(gamma_cam*relu(BN(apre)) + input); LDS tile-transpose
// makes the global bf16 store a contiguous short4 stream.
__global__ __launch_bounds__(256) void k_bn1t(
    const float* __restrict__ apre, const float* __restrict__ inp,
    const float* __restrict__ stats, const float* __restrict__ gamma,
    const float* __restrict__ beta, const float* __restrict__ gcam,
    short* __restrict__ mid_t)
{
    __shared__ short t[64 * C];     // [px_local][c]
    int b = blockIdx.y;
    int n0 = blockIdx.x * 64;
    int tid = threadIdx.x;
    const float invc = 1.0f / (float)CNT;
    float g = gcam[0];

#pragma unroll
    for (int it = 0; it < 3; ++it) {
        int e = tid + it * 256;                 // 0..767 = 48 ch x 16 px-quads
        int c = e >> 4, pq = (e & 15) * 4;
        float mu = stats[c] * invc;
        float var = stats[C + c] * invc - mu * mu;
        float sc = gamma[c] * rsqrtf(var + 1e-5f);
        float be = beta[c] - mu * sc;
        size_t base = ((size_t)b * C + c) * NPIX + n0 + pq;
        float4 v = *(const float4*)(apre + base);
        float4 x = *(const float4*)(inp + base);
        t[(pq + 0) * C + c] = f2bfs(fmaxf(v.x * sc + be, 0.f) * g + x.x);
        t[(pq + 1) * C + c] = f2bfs(fmaxf(v.y * sc + be, 0.f) * g + x.y);
        t[(pq + 2) * C + c] = f2bfs(fmaxf(v.z * sc + be, 0.f) * g + x.z);
        t[(pq + 3) * C + c] = f2bfs(fmaxf(v.w * sc + be, 0.f) * g + x.w);
    }
    __syncthreads();
    short* mb = mid_t + ((size_t)b * NPIX + n0) * C;
#pragma unroll
    for (int it = 0; it < 3; ++it) {
        int e = tid + it * 256;                 // contiguous: row = 12 short4s
        *(short4*)(mb + e * 4) = *(const short4*)&t[e * 4];
    }
}

// ---------------------------------------------------------------- k_prep
__global__ __launch_bounds__(256) void k_prep(
    const float* __restrict__ outw, short* __restrict__ Wb)
{
    int idx = blockIdx.x * 256 + threadIdx.x;
    if (idx >= 9 * 48 * 64) return;
    int i = idx & 63;
    int o = (idx >> 6) % 48;
    int tap = idx / (64 * 48);
    float v = (i < C) ? outw[((size_t)o * C + i) * 9 + tap] : 0.f;
    Wb[idx] = f2bfs(v);
}

// ---------------------------------------------------------------- k_conv_mfma
__global__ __launch_bounds__(256) void k_conv_mfma(
    const short* __restrict__ mid_t, const short* __restrict__ Wb,
    const float* __restrict__ bias, float* __restrict__ out,
    float* __restrict__ stats)
{
    __shared__ short xl[324 * 72];
    __shared__ float sst[96];
    int b = blockIdx.y;
    int ty = blockIdx.x / 12, tx = blockIdx.x % 12;
    int h0 = ty * 16, w0 = tx * 16;
    int tid = threadIdx.x;

    if (tid < 96) sst[tid] = 0.f;

    for (int ch = tid; ch < 2916; ch += 256) {
        int lpx = ch / 9, part = ch % 9;
        int hh = h0 - 1 + lpx / 18, ww = w0 - 1 + lpx % 18;
        short8 v = {0, 0, 0, 0, 0, 0, 0, 0};
        if (part < 6 && hh >= 0 && hh < HW && ww >= 0 && ww < HW)
            v = *(const short8*)(mid_t + ((size_t)b * NPIX + hh * HW + ww) * C + part * 8);
        *(short8*)(xl + lpx * 72 + part * 8) = v;
    }
    __syncthreads();

    int wid = tid >> 6, lane = tid & 63;
    int col = lane & 15, quad = lane >> 4;

    f32x4 acc[3][4];
#pragma unroll
    for (int mt = 0; mt < 3; ++mt)
#pragma unroll
        for (int rr = 0; rr < 4; ++rr)
            acc[mt][rr] = (f32x4){0.f, 0.f, 0.f, 0.f};

#pragma unroll
    for (int tap = 0; tap < 9; ++tap) {
        int dh = tap / 3, dw = tap % 3;
#pragma unroll
        for (int kb = 0; kb < 2; ++kb) {
            short8 afr[3];
#pragma unroll
            for (int mt = 0; mt < 3; ++mt)
                afr[mt] = *(const short8*)(Wb + ((size_t)(tap * 48 + mt * 16 + col)) * 64
                                               + kb * 32 + quad * 8);
#pragma unroll
            for (int rr = 0; rr < 4; ++rr) {
                int r = wid * 4 + rr;
                int lpx = (r + dh) * 18 + col + dw;
                short8 bfr = *(const short8*)(xl + lpx * 72 + kb * 32 + quad * 8);
#pragma unroll
                for (int mt = 0; mt < 3; ++mt)
                    acc[mt][rr] = __builtin_amdgcn_mfma_f32_16x16x32_bf16(
                        afr[mt], bfr, acc[mt][rr], 0, 0, 0);
            }
        }
    }

    float s1[3][4] = {}, s2[3][4] = {};
#pragma unroll
    for (int mt = 0; mt < 3; ++mt)
#pragma unroll
        for (int rr = 0; rr < 4; ++rr) {
            int r = wid * 4 + rr;
            f32x4 v = acc[mt][rr];
#pragma unroll
            for (int j = 0; j < 4; ++j) {
                int o = mt * 16 + quad * 4 + j;
                float val = v[j] + bias[o];
                out[((size_t)b * C + o) * NPIX + (h0 + r) * HW + w0 + col] = val;
                s1[mt][j] += val;
                s2[mt][j] += val * val;
            }
        }
#pragma unroll
    for (int mt = 0; mt < 3; ++mt)
#pragma unroll
        for (int j = 0; j < 4; ++j) {
            float a = s1[mt][j], q = s2[mt][j];
#pragma unroll
            for (int off = 8; off; off >>= 1) {
                a += __shfl_down(a, off, 16);
                q += __shfl_down(q, off, 16);
            }
            if (col == 0) {
                int o = mt * 16 + quad * 4 + j;
                atomicAdd(&sst[o], a);
                atomicAdd(&sst[48 + o], q);
            }
        }
    __syncthreads();
    if (tid < 48)       atomicAdd(&stats[2 * C + tid], sst[tid]);
    else if (tid < 96)  atomicAdd(&stats[3 * C + tid - 48], sst[tid]);
}

// ---------------------------------------------------------------- k_bn2
__global__ __launch_bounds__(256) void k_bn2(
    float* __restrict__ out, const float* __restrict__ stats,
    const float* __restrict__ gamma, const float* __restrict__ beta)
{
    size_t i = ((size_t)blockIdx.x * 256 + threadIdx.x) * 4;
    int c = (int)((i / NPIX) % C);
    const float invc = 1.0f / (float)CNT;
    float mu = stats[2 * C + c] * invc;
    float var = stats[3 * C + c] * invc - mu * mu;
    float sc = gamma[c] * rsqrtf(var + 1e-5f);
    float be = beta[c] - mu * sc;

    float4 v = *(float4*)(out + i);
    v.x = fmaxf(v.x * sc + be, 0.f);
    v.y = fmaxf(v.y * sc + be, 0.f);
    v.z = fmaxf(v.z * sc + be, 0.f);
    v.w = fmaxf(v.w * sc + be, 0.f);
    *(float4*)(out + i) = v;
}

// ---------------------------------------------------------------- launch
extern "C" void kernel_launch(void* const* d_in, const int* in_sizes, int n_in,
                              void* d_out, int out_size, void* d_ws, size_t ws_size,
                              hipStream_t stream)
{
    const float* inp   = (const float*)d_in[0];
    const float* fb    = (const float*)d_in[1];
    const float* fc    = (const float*)d_in[2];
    const float* fd    = (const float*)d_in[3];
    const float* Wa    = (const float*)d_in[4];
    const float* Wbm   = (const float*)d_in[5];
    const float* Wcm   = (const float*)d_in[6];
    const float* Wdm   = (const float*)d_in[7];
    const float* fusew = (const float*)d_in[8];
    const float* fuseb = (const float*)d_in[9];
    const float* fgam  = (const float*)d_in[10];
    const float* fbet  = (const float*)d_in[11];
    const float* gcam  = (const float*)d_in[12];
    const float* outw  = (const float*)d_in[13];
    const float* outb  = (const float*)d_in[14];
    const float* ogam  = (const float*)d_in[15];
    const float* obet  = (const float*)d_in[16];

    float* ws    = (float*)d_ws;
    float* apre  = ws + APRE_OFF;
    float* G     = ws + G_OFF;
    float* stats = ws + STATS_OFF;
    float* M2g   = ws + M2_OFF;
    short* mid_t = (short*)((char*)d_ws + MIDT_BYTE);
    short* Wb    = (short*)((char*)d_ws + WB_BYTE);
    float* out   = (float*)d_out;

    hipMemsetAsync(G, 0, (73728ull + 192ull) * sizeof(float), stream);

    k_prep<<<108, 256, 0, stream>>>(outw, Wb);
    k_gram_mfma<<<dim3(144, BATCH), 256, 0, stream>>>(inp, fb, fc, fd, G);
    k_small<<<dim3(4, BATCH), 256, 0, stream>>>(G, Wa, Wbm, Wcm, Wdm, fusew, M2g);
    k_apply_mfma<<<dim3(144, BATCH), 256, 0, stream>>>(inp, fb, fc, fd, M2g, fuseb, apre, stats);
    k_bn1t<<<dim3(576, BATCH), 256, 0, stream>>>(apre, inp, stats, fgam, fbet, gcam, mid_t);
    k_conv_mfma<<<dim3(144, BATCH), 256, 0, stream>>>(mid_t, Wb, outb, out, stats);
    k_bn2<<<13824, 256, 0, stream>>>(out, stats, ogam, obet);
}